// Round 1
// baseline (320.683 us; speedup 1.0000x reference)
//
#include <hip/hip_runtime.h>
#include <hip/hip_bf16.h>

typedef __attribute__((ext_vector_type(8))) short short8;
typedef __attribute__((ext_vector_type(4))) float f32x4;

// ---------- helpers ----------
__device__ __forceinline__ short bf16rne(float x) {
    unsigned u = __float_as_uint(x);
    u = (u + 0x7FFFu + ((u >> 16) & 1u)) >> 16;
    return (short)u;
}

// Sizes
#define NNODES 4800
#define KT 96            // k-tile (4800 = 50*96)
#define KSPLIT 2         // 25 tiles per split

// ---------- K0: weight transposes (bf16) + ones-blocks of HbT ----------
__global__ void k0_prep(const float* __restrict__ W2, const float* __restrict__ P1,
                        const float* __restrict__ P2,
                        short* __restrict__ W2T, short* __restrict__ P1T, short* __restrict__ P2T,
                        short* __restrict__ HbT1, short* __restrict__ HbT2) {
    int idx = blockIdx.x * 256 + threadIdx.x;
    if (idx < 73728) { // W2T[384][192] from W2[192][384]
        int n = idx / 192, k = idx % 192;
        W2T[idx] = bf16rne(W2[k * 384 + n]);
        return;
    }
    idx -= 73728;
    if (idx < 20480) { // P1T[128][160] from P1[143][128], k>=143 zero
        int n = idx / 160, k = idx % 160;
        P1T[idx] = bf16rne(k < 143 ? P1[k * 128 + n] : 0.f);
        return;
    }
    idx -= 20480;
    if (idx < 8192) { // P2T[64][128] from P2[128][64]
        int n = idx / 128, k = idx % 128;
        P2T[idx] = bf16rne(P2[k * 64 + n]);
        return;
    }
    idx -= 8192;
    if (idx < 230400) { // HbT1 ones-block rows 64..79
        int i = idx % NNODES, r = idx / NNODES, nn = r % 16, h = r / 16;
        HbT1[(size_t)(h * 80 + 64 + nn) * NNODES + i] = (nn == 0) ? (short)0x3F80 : (short)0;
        return;
    }
    idx -= 230400;
    if (idx < 230400) { // HbT2 ones-block rows 128..143
        int i = idx % NNODES, r = idx / NNODES, nn = r % 16, h = r / 16;
        HbT2[(size_t)(h * 144 + 128 + nn) * NNODES + i] = (nn == 0) ? (short)0x3F80 : (short)0;
        return;
    }
}

// ---------- K1: h1 = flat @ W1 ; s1/t1 head dots. block=192thr, grid=4800 ----------
__global__ void k1_h1(const float* __restrict__ flat, const float* __restrict__ W1,
                      const float* __restrict__ a_src, const float* __restrict__ a_dst,
                      float* __restrict__ h1, float* __restrict__ s1, float* __restrict__ t1) {
    __shared__ float fl[16];
    const int i = blockIdx.x, tid = threadIdx.x;
    if (tid < 15) fl[tid] = flat[i * 15 + tid];
    __syncthreads();
    float hv = 0.f;
#pragma unroll
    for (int f = 0; f < 15; ++f) hv += fl[f] * W1[f * 192 + tid];
    h1[(size_t)i * 192 + tid] = hv;
    float ps = hv * a_src[tid];   // a_src is [3][64] contiguous == [192]
    float pt = hv * a_dst[tid];
#pragma unroll
    for (int off = 32; off; off >>= 1) {
        ps += __shfl_xor(ps, off);
        pt += __shfl_xor(pt, off);
    }
    if ((tid & 63) == 0) {
        int h = tid >> 6;
        s1[h * NNODES + i] = ps;
        t1[h * NNODES + i] = pt;
    }
}

// ---------- K_T: fp32 [4800][H*D] -> bf16 transposed [H][Neff][4800] (rows < D) ----------
__global__ void k_trans(const float* __restrict__ src, short* __restrict__ dst,
                        int HD, int D, int Neff, int total) {
    int idx = blockIdx.x * 256 + threadIdx.x;
    if (idx >= total) return;
    int i = idx % NNODES;
    int rest = idx / NNODES;
    int h = rest / D, n = rest % D;
    dst[(size_t)(h * Neff + n) * NNODES + i] = bf16rne(src[(size_t)i * HD + h * D + n]);
}

// ---------- K2: flash-GAT attention. grid (75, 3 heads, KSPLIT), block 256 ----------
// O_part[kc][h][i][0..Neff) = sum_j exp(lrelu(s_i+t_j)) * Hb[j][*]  (col D.. has ones col -> denominator)
template <int NT>
__global__ __launch_bounds__(256) void k2_attn(const float* __restrict__ s, const float* __restrict__ t,
                                               const short* __restrict__ HbT, float* __restrict__ opart) {
    constexpr int NR = NT * 16;
    __shared__ __align__(16) short Bt[NR][KT + 8];
    __shared__ __align__(16) float tt[KT];
    const int tid = threadIdx.x;
    const int lane = tid & 63;
    const int w = tid >> 6;
    const int q = lane >> 4;
    const int mr = lane & 15;
    const int h = blockIdx.y;
    const int kc = blockIdx.z;
    const int m0 = blockIdx.x * 64 + w * 16;

    const float sv = s[h * NNODES + m0 + mr];

    f32x4 acc[NT];
#pragma unroll
    for (int n = 0; n < NT; ++n) acc[n] = (f32x4){0.f, 0.f, 0.f, 0.f};

    const short* hb = HbT + (size_t)h * NR * NNODES;
    for (int tile = 0; tile < 25; ++tile) {
        const int k0 = kc * (25 * KT) + tile * KT;
        // stage B tile [NR][96] (+8 pad) via b128
        for (int c = tid; c < NR * 12; c += 256) {
            int n = c / 12, ko = (c - n * 12) * 8;
            *(short8*)&Bt[n][ko] = *(const short8*)(hb + (size_t)n * NNODES + k0 + ko);
        }
        if (tid < KT) tt[tid] = t[h * NNODES + k0 + tid];
        __syncthreads();
#pragma unroll
        for (int ks = 0; ks < 3; ++ks) {
            const float4* tp = (const float4*)&tt[ks * 32 + q * 8];
            float4 ta = tp[0], tb = tp[1];
            float tv[8] = {ta.x, ta.y, ta.z, ta.w, tb.x, tb.y, tb.z, tb.w};
            short8 af;
#pragma unroll
            for (int j = 0; j < 8; ++j) {
                float x = sv + tv[j];
                x = fmaxf(x, 0.2f * x);            // leaky_relu(., 0.2)
                af[j] = bf16rne(__expf(x));        // no max-shift needed: |x| bounded
            }
#pragma unroll
            for (int n = 0; n < NT; ++n) {
                short8 bf = *(const short8*)&Bt[n * 16 + mr][ks * 32 + q * 8];
                acc[n] = __builtin_amdgcn_mfma_f32_16x16x32_bf16(af, bf, acc[n], 0, 0, 0);
            }
        }
        __syncthreads();
    }
    // epilogue: D layout col=lane&15, row=q*4+r
#pragma unroll
    for (int n = 0; n < NT; ++n) {
#pragma unroll
        for (int r = 0; r < 4; ++r) {
            int row = m0 + q * 4 + r;
            opart[(size_t)((kc * 3 + h) * NNODES + row) * NR + n * 16 + mr] = acc[n][r];
        }
    }
}

// ---------- K3a: layer1 epilogue: (p0+p1)/(l0+l1), ELU, -> bf16 [4800][192] ----------
__global__ void k3a_epi(const float* __restrict__ op, short* __restrict__ h1abf) {
    int idx = blockIdx.x * 256 + threadIdx.x;
    if (idx >= NNODES * 192) return;
    int i = idx / 192, c = idx % 192;
    int h = c >> 6, d = c & 63;
    const float* p0 = op + (size_t)(h * NNODES + i) * 80;
    const float* p1 = op + (size_t)((3 + h) * NNODES + i) * 80;
    float v = (p0[d] + p1[d]) / (p0[64] + p1[64]);
    v = v > 0.f ? v : (__expf(v) - 1.f);           // ELU
    h1abf[idx] = bf16rne(v);
}

// ---------- generic bf16 MFMA GEMM: C[M,N] = A[M,K] @ BT[N,K]^T (+bias, relu) ----------
__global__ __launch_bounds__(256) void gemm_bf16(const short* __restrict__ A, const short* __restrict__ BT,
                                                 const float* __restrict__ bias,
                                                 float* __restrict__ Cf, short* __restrict__ Cb,
                                                 int N, int K, int relu) {
    const int tid = threadIdx.x;
    const int lane = tid & 63;
    const int w = tid >> 6;
    const int q = lane >> 4;
    const int mr = lane & 15;
    const int m = blockIdx.x * 64 + w * 16 + mr;   // A row for A-frag
    const int n0 = blockIdx.y * 64;

    f32x4 acc[4];
#pragma unroll
    for (int n = 0; n < 4; ++n) acc[n] = (f32x4){0.f, 0.f, 0.f, 0.f};

    for (int k0 = 0; k0 < K; k0 += 32) {
        short8 af = *(const short8*)(A + (size_t)m * K + k0 + q * 8);
#pragma unroll
        for (int n = 0; n < 4; ++n) {
            short8 bf = *(const short8*)(BT + (size_t)(n0 + n * 16 + mr) * K + k0 + q * 8);
            acc[n] = __builtin_amdgcn_mfma_f32_16x16x32_bf16(af, bf, acc[n], 0, 0, 0);
        }
    }
#pragma unroll
    for (int n = 0; n < 4; ++n) {
        int col = n0 + n * 16 + mr;
        float bv = bias ? bias[col] : 0.f;
#pragma unroll
        for (int r = 0; r < 4; ++r) {
            int row = blockIdx.x * 64 + w * 16 + q * 4 + r;
            float v = acc[n][r] + bv;
            if (relu) v = fmaxf(v, 0.f);
            if (Cf) Cf[(size_t)row * N + col] = v;
            if (Cb) Cb[(size_t)row * N + col] = bf16rne(v);
        }
    }
}

// ---------- K5: s2/t2 head dots from h2 [4800][384] ----------
__global__ void k5_st2(const float* __restrict__ h2, const float* __restrict__ a_src2,
                       const float* __restrict__ a_dst2, float* __restrict__ s2, float* __restrict__ t2) {
    int idx = blockIdx.x * 256 + threadIdx.x;
    if (idx >= 3 * NNODES) return;
    int h = idx / NNODES, i = idx % NNODES;
    const float4* hp = (const float4*)(h2 + (size_t)i * 384 + h * 128);
    const float4* as = (const float4*)(a_src2 + h * 128);
    const float4* ad = (const float4*)(a_dst2 + h * 128);
    float s = 0.f, t = 0.f;
#pragma unroll
    for (int d = 0; d < 32; ++d) {
        float4 hv = hp[d], av = as[d], bv = ad[d];
        s += hv.x * av.x + hv.y * av.y + hv.z * av.z + hv.w * av.w;
        t += hv.x * bv.x + hv.y * bv.y + hv.z * bv.z + hv.w * bv.w;
    }
    s2[idx] = s;
    t2[idx] = t;
}

// ---------- K3b: layer2 epilogue: mean heads, concat flat -> g bf16 [4800][160] ----------
__global__ void k3b_epi(const float* __restrict__ op, const float* __restrict__ flat,
                        short* __restrict__ gbf) {
    int idx = blockIdx.x * 256 + threadIdx.x;
    if (idx >= NNODES * 160) return;
    int i = idx / 160, c = idx % 160;
    float v;
    if (c < 128) {
        float a = 0.f;
#pragma unroll
        for (int h = 0; h < 3; ++h) {
            const float* p0 = op + (size_t)(h * NNODES + i) * 144;
            const float* p1 = op + (size_t)((3 + h) * NNODES + i) * 144;
            a += (p0[c] + p1[c]) / (p0[128] + p1[128]);
        }
        v = a * (1.f / 3.f);
    } else if (c < 143) {
        v = flat[i * 15 + (c - 128)];
    } else {
        v = 0.f;
    }
    gbf[idx] = bf16rne(v);
}

// ---------- K8: mean-pool over jobs + mask passthrough ----------
__global__ void k8_pool(const float* __restrict__ f2, const float* __restrict__ mask,
                        float* __restrict__ out) {
    int idx = blockIdx.x * 256 + threadIdx.x;
    if (idx < 2048) {
        int b = idx >> 6, d = idx & 63;
        float s = 0.f;
        for (int j = 0; j < 150; ++j) s += f2[(size_t)(b * 150 + j) * 64 + d];
        out[idx] = s * (1.f / 150.f);
    } else if (idx < 2048 + 4832) {
        out[idx] = mask[idx - 2048];
    }
}

extern "C" void kernel_launch(void* const* d_in, const int* in_sizes, int n_in,
                              void* d_out, int out_size, void* d_ws, size_t ws_size,
                              hipStream_t stream) {
    const float* flat   = (const float*)d_in[0];
    const float* amask  = (const float*)d_in[1];
    const float* W1     = (const float*)d_in[2];
    const float* a_src1 = (const float*)d_in[3];
    const float* a_dst1 = (const float*)d_in[4];
    const float* W2     = (const float*)d_in[5];
    const float* a_src2 = (const float*)d_in[6];
    const float* a_dst2 = (const float*)d_in[7];
    const float* P1     = (const float*)d_in[8];
    const float* b1     = (const float*)d_in[9];
    const float* P2     = (const float*)d_in[10];
    const float* b2     = (const float*)d_in[11];
    float* out = (float*)d_out;

    float* ws = (float*)d_ws;
    // layout (float offsets); opart2 aliases dead layer-1 buffers
    float* h1    = ws + 0;                     //  921600
    float* s1    = ws + 921600;                //   14400
    float* t1    = ws + 936000;                //   14400
    short* HbT1  = (short*)(ws + 950400);      //  576000 f (3*80*4800 bf16)
    float* op1   = ws + 1526400;               // 2304000 (2*3*4800*80)
    short* h1abf = (short*)(ws + 3830400);     //  460800 f (4800*192 bf16)
    float* h2    = ws + 4291200;               // 1843200 (4800*384)
    float* s2    = ws + 6134400;               //   14400
    float* t2    = ws + 6148800;               //   14400
    short* HbT2  = (short*)(ws + 6163200);     // 1036800 f (3*144*4800 bf16)
    short* gbf   = (short*)(ws + 7200000);     //  384000 f (4800*160 bf16)
    short* f1bf  = (short*)(ws + 7584000);     //  307200 f (4800*128 bf16)
    float* f2    = ws + 7891200;               //  307200 (4800*64)
    short* W2T   = (short*)(ws + 8198400);     //   36864 f
    short* P1T   = (short*)(ws + 8235264);     //   10240 f
    short* P2T   = (short*)(ws + 8245504);     //    4096 f
    float* op2   = ws + 0;                     // 4147200 (2*3*4800*144) — aliases h1/s1/t1/HbT1/op1/h1abf (all dead)

    k0_prep<<<2200, 256, 0, stream>>>(W2, P1, P2, W2T, P1T, P2T, HbT1, HbT2);
    k1_h1<<<NNODES, 192, 0, stream>>>(flat, W1, a_src1, a_dst1, h1, s1, t1);
    k_trans<<<3600, 256, 0, stream>>>(h1, HbT1, 192, 64, 80, NNODES * 192);
    k2_attn<5><<<dim3(75, 3, KSPLIT), 256, 0, stream>>>(s1, t1, HbT1, op1);
    k3a_epi<<<3600, 256, 0, stream>>>(op1, h1abf);
    gemm_bf16<<<dim3(75, 6), 256, 0, stream>>>(h1abf, W2T, nullptr, h2, nullptr, 384, 192, 0);
    k5_st2<<<57, 256, 0, stream>>>(h2, a_src2, a_dst2, s2, t2);
    k_trans<<<7200, 256, 0, stream>>>(h2, HbT2, 384, 128, 144, NNODES * 384);
    k2_attn<9><<<dim3(75, 3, KSPLIT), 256, 0, stream>>>(s2, t2, HbT2, op2);
    k3b_epi<<<3000, 256, 0, stream>>>(op2, flat, gbf);
    gemm_bf16<<<dim3(75, 2), 256, 0, stream>>>(gbf, P1T, b1, nullptr, f1bf, 128, 160, 1);
    gemm_bf16<<<dim3(75, 1), 256, 0, stream>>>(f1bf, P2T, b2, f2, nullptr, 64, 128, 1);
    k8_pool<<<27, 256, 0, stream>>>(f2, amask, out);
}

// Round 2
// 314.700 us; speedup vs baseline: 1.0190x; 1.0190x over previous
//
#include <hip/hip_runtime.h>
#include <hip/hip_bf16.h>

typedef __attribute__((ext_vector_type(8))) short short8;
typedef __attribute__((ext_vector_type(4))) float f32x4;

__device__ __forceinline__ short bf16rne(float x) {
    unsigned u = __float_as_uint(x);
    u = (u + 0x7FFFu + ((u >> 16) & 1u)) >> 16;
    return (short)u;
}

#define NN 4800
#define NCHUNK 64
#define CLEN 75      // 64*75 = 4800
#define KCH 8
#define KLEN 600     // 8*600 = 4800

// ---------- K0: weight transposes to bf16 ----------
__global__ void k0_prep(const float* __restrict__ W2, const float* __restrict__ P1,
                        const float* __restrict__ P2,
                        short* __restrict__ W2T, short* __restrict__ P1T, short* __restrict__ P2T) {
    int idx = blockIdx.x * 256 + threadIdx.x;
    if (idx < 73728) { int n = idx / 192, k = idx % 192; W2T[idx] = bf16rne(W2[k * 384 + n]); return; }
    idx -= 73728;
    if (idx < 20480) { int n = idx / 160, k = idx % 160; P1T[idx] = bf16rne(k < 143 ? P1[k * 128 + n] : 0.f); return; }
    idx -= 20480;
    if (idx < 8192)  { int n = idx / 128, k = idx % 128; P2T[idx] = bf16rne(P2[k * 64 + n]); }
}

// ---------- K1: h1 = flat @ W1 ; s1/t1 head dots ----------
__global__ void k1_h1(const float* __restrict__ flat, const float* __restrict__ W1,
                      const float* __restrict__ a_src, const float* __restrict__ a_dst,
                      float* __restrict__ h1, float* __restrict__ s1, float* __restrict__ t1) {
    __shared__ float fl[16];
    const int i = blockIdx.x, tid = threadIdx.x;
    if (tid < 15) fl[tid] = flat[i * 15 + tid];
    __syncthreads();
    float hv = 0.f;
#pragma unroll
    for (int f = 0; f < 15; ++f) hv += fl[f] * W1[f * 192 + tid];
    h1[(size_t)i * 192 + tid] = hv;
    float ps = hv * a_src[tid];
    float pt = hv * a_dst[tid];
#pragma unroll
    for (int off = 32; off; off >>= 1) {
        ps += __shfl_xor(ps, off);
        pt += __shfl_xor(pt, off);
    }
    if ((tid & 63) == 0) {
        int h = tid >> 6;
        s1[h * NN + i] = ps;
        t1[h * NN + i] = pt;
    }
}

// ---------- krank: partial rank counts. queries: q<NN -> rank of t_q (tie by idx);
//            q>=NN -> r_i = #{j: t_j <= -s_i}. grid (38, 3, KCH) ----------
__global__ void krank(const float* __restrict__ s, const float* __restrict__ t,
                      int* __restrict__ partial) {
    __shared__ float ts[KLEN];
    const int h = blockIdx.y, kc = blockIdx.z;
    const float* tb_ = t + h * NN + kc * KLEN;
    for (int k = threadIdx.x; k < KLEN; k += 256) ts[k] = tb_[k];
    __syncthreads();
    int q = blockIdx.x * 256 + threadIdx.x;
    if (q >= 2 * NN) return;
    float u; int tb;
    if (q < NN) { u = t[h * NN + q]; tb = q - kc * KLEN; }   // local-index tiebreak
    else        { u = -s[h * NN + q - NN]; tb = KLEN; }       // <= semantics
    int cnt = 0;
    for (int k = 0; k < KLEN; ++k) {
        float tk = ts[k];
        cnt += (tk < u) || (tk == u && k < tb);
    }
    partial[(kc * 3 + h) * (2 * NN) + q] = cnt;
}

// ---------- krankred: sum partials -> inv perm, ranks, exp tables ----------
__global__ void krankred(const float* __restrict__ t, const int* __restrict__ partial,
                         int* __restrict__ inv, int* __restrict__ rk,
                         float* __restrict__ e1, float* __restrict__ e2) {
    int idx = blockIdx.x * 256 + threadIdx.x;
    if (idx >= 3 * 2 * NN) return;
    int h = idx / (2 * NN), q = idx % (2 * NN);
    int sum = 0;
#pragma unroll
    for (int kc = 0; kc < KCH; ++kc) sum += partial[(kc * 3 + h) * (2 * NN) + q];
    if (q < NN) {
        float tv = t[h * NN + q];
        e1[h * NN + q] = __expf(tv);
        e2[h * NN + q] = __expf(0.2f * tv);
        inv[h * NN + sum] = q;          // bijection via index tiebreak
    } else {
        rk[h * NN + q - NN] = sum;
    }
}

// ---------- phA: chunk totals (fp64). grid (64, 3), block>=Dc ----------
__global__ void phA(const float* __restrict__ hsrc, const int* __restrict__ inv,
                    const float* __restrict__ e1, const float* __restrict__ e2,
                    double* __restrict__ Tot1, double* __restrict__ Tot2,
                    int HD, int Dd, int Dc) {
    const int c = blockIdx.x, h = blockIdx.y, d = threadIdx.x;
    if (d >= Dc) return;
    double a1 = 0, a2 = 0;
    for (int p0 = 0; p0 < CLEN; ++p0) {
        int j = inv[h * NN + c * CLEN + p0];
        float f1 = e1[h * NN + j], f2 = e2[h * NN + j];
        float hv = (d < Dd) ? hsrc[(size_t)j * HD + h * Dd + d] : 1.f;
        a1 += (double)f1 * hv;
        a2 += (double)f2 * hv;
    }
    Tot1[(h * NCHUNK + c) * Dc + d] = a1;
    Tot2[(h * NCHUNK + c) * Dc + d] = a2;
}

// ---------- phB: scan chunk totals -> chunk offsets ----------
__global__ void phB(const double* __restrict__ Tot1, const double* __restrict__ Tot2,
                    double* __restrict__ Off1, double* __restrict__ Off2, int Dc) {
    int idx = blockIdx.x * 256 + threadIdx.x;
    if (idx >= 3 * Dc * 2) return;
    int dir = idx / (3 * Dc);
    int rest = idx % (3 * Dc);
    int h = rest / Dc, d = rest % Dc;
    if (dir == 0) {           // suffix offsets for e1 array
        double r = 0;
        Off1[(h * NCHUNK + NCHUNK - 1) * Dc + d] = 0;
        for (int c = NCHUNK - 2; c >= 0; --c) {
            r += Tot1[(h * NCHUNK + c + 1) * Dc + d];
            Off1[(h * NCHUNK + c) * Dc + d] = r;
        }
    } else {                  // prefix offsets for e2 array
        double r = 0;
        Off2[(h * NCHUNK + 0) * Dc + d] = 0;
        for (int c = 1; c < NCHUNK; ++c) {
            r += Tot2[(h * NCHUNK + c - 1) * Dc + d];
            Off2[(h * NCHUNK + c) * Dc + d] = r;
        }
    }
}

// ---------- phC: write full prefix (exclusive, e2) / suffix (inclusive, e1) arrays ----------
__global__ void phC(const float* __restrict__ hsrc, const int* __restrict__ inv,
                    const float* __restrict__ e1, const float* __restrict__ e2,
                    const double* __restrict__ Off1, const double* __restrict__ Off2,
                    float* __restrict__ Suf1, float* __restrict__ Pre2,
                    int HD, int Dd, int Dc) {
    const int c = blockIdx.x, h = blockIdx.y, d = threadIdx.x;
    if (d >= Dc) return;
    double r2 = Off2[(h * NCHUNK + c) * Dc + d];
    for (int p0 = 0; p0 < CLEN; ++p0) {
        int p = c * CLEN + p0;
        int j = inv[h * NN + p];
        float hv = (d < Dd) ? hsrc[(size_t)j * HD + h * Dd + d] : 1.f;
        Pre2[((size_t)h * (NN + 1) + p) * Dc + d] = (float)r2;
        r2 += (double)e2[h * NN + j] * hv;
    }
    if (c == NCHUNK - 1) {
        Pre2[((size_t)h * (NN + 1) + NN) * Dc + d] = (float)r2;
        Suf1[((size_t)h * (NN + 1) + NN) * Dc + d] = 0.f;
    }
    double r1 = Off1[(h * NCHUNK + c) * Dc + d];
    for (int p0 = CLEN - 1; p0 >= 0; --p0) {
        int p = c * CLEN + p0;
        int j = inv[h * NN + p];
        float hv = (d < Dd) ? hsrc[(size_t)j * HD + h * Dd + d] : 1.f;
        r1 += (double)e1[h * NN + j] * hv;
        Suf1[((size_t)h * (NN + 1) + p) * Dc + d] = (float)r1;
    }
}

// ---------- kout1: combine + ELU -> h1a bf16 [4800][192]. grid 4800, block 192 ----------
__global__ void kout1(const float* __restrict__ s, const int* __restrict__ rk,
                      const float* __restrict__ Suf1, const float* __restrict__ Pre2,
                      short* __restrict__ h1abf) {
    const int i = blockIdx.x, tid = threadIdx.x;
    const int h = tid >> 6, d = tid & 63;
    float sv = s[h * NN + i];
    float es1 = __expf(sv), es2 = __expf(0.2f * sv);
    int r = rk[h * NN + i];
    size_t base = ((size_t)h * (NN + 1) + r) * 65;
    float num = es1 * Suf1[base + d] + es2 * Pre2[base + d];
    float den = es1 * Suf1[base + 64] + es2 * Pre2[base + 64];
    float v = num / den;
    v = v > 0.f ? v : (__expf(v) - 1.f);
    h1abf[(size_t)i * 192 + tid] = bf16rne(v);
}

// ---------- kout2: combine + head-mean + concat flat -> g bf16 [4800][160]. block 192 ----------
__global__ void kout2(const float* __restrict__ s, const int* __restrict__ rk,
                      const float* __restrict__ Suf1, const float* __restrict__ Pre2,
                      const float* __restrict__ flat, short* __restrict__ gbf) {
    const int i = blockIdx.x, tid = threadIdx.x;
    if (tid < 128) {
        float acc = 0.f;
#pragma unroll
        for (int h = 0; h < 3; ++h) {
            float sv = s[h * NN + i];
            float es1 = __expf(sv), es2 = __expf(0.2f * sv);
            int r = rk[h * NN + i];
            size_t base = ((size_t)h * (NN + 1) + r) * 129;
            float num = es1 * Suf1[base + tid] + es2 * Pre2[base + tid];
            float den = es1 * Suf1[base + 128] + es2 * Pre2[base + 128];
            acc += num / den;
        }
        gbf[(size_t)i * 160 + tid] = bf16rne(acc * (1.f / 3.f));
    } else if (tid < 160) {
        float v = (tid < 143) ? flat[i * 15 + (tid - 128)] : 0.f;
        gbf[(size_t)i * 160 + tid] = bf16rne(v);
    }
}

// ---------- generic bf16 MFMA GEMM: C[M,N] = A[M,K] @ BT[N,K]^T (+bias, relu) ----------
__global__ __launch_bounds__(256) void gemm_bf16(const short* __restrict__ A, const short* __restrict__ BT,
                                                 const float* __restrict__ bias,
                                                 float* __restrict__ Cf, short* __restrict__ Cb,
                                                 int N, int K, int relu) {
    const int tid = threadIdx.x;
    const int lane = tid & 63;
    const int w = tid >> 6;
    const int q = lane >> 4;
    const int mr = lane & 15;
    const int m = blockIdx.x * 64 + w * 16 + mr;
    const int n0 = blockIdx.y * 64;

    f32x4 acc[4];
#pragma unroll
    for (int n = 0; n < 4; ++n) acc[n] = (f32x4){0.f, 0.f, 0.f, 0.f};

    for (int k0 = 0; k0 < K; k0 += 32) {
        short8 af = *(const short8*)(A + (size_t)m * K + k0 + q * 8);
#pragma unroll
        for (int n = 0; n < 4; ++n) {
            short8 bf = *(const short8*)(BT + (size_t)(n0 + n * 16 + mr) * K + k0 + q * 8);
            acc[n] = __builtin_amdgcn_mfma_f32_16x16x32_bf16(af, bf, acc[n], 0, 0, 0);
        }
    }
#pragma unroll
    for (int n = 0; n < 4; ++n) {
        int col = n0 + n * 16 + mr;
        float bv = bias ? bias[col] : 0.f;
#pragma unroll
        for (int r = 0; r < 4; ++r) {
            int row = blockIdx.x * 64 + w * 16 + q * 4 + r;
            float v = acc[n][r] + bv;
            if (relu) v = fmaxf(v, 0.f);
            if (Cf) Cf[(size_t)row * N + col] = v;
            if (Cb) Cb[(size_t)row * N + col] = bf16rne(v);
        }
    }
}

// ---------- K5: s2/t2 head dots from h2 [4800][384] ----------
__global__ void k5_st2(const float* __restrict__ h2, const float* __restrict__ a_src2,
                       const float* __restrict__ a_dst2, float* __restrict__ s2, float* __restrict__ t2) {
    int idx = blockIdx.x * 256 + threadIdx.x;
    if (idx >= 3 * NN) return;
    int h = idx / NN, i = idx % NN;
    const float4* hp = (const float4*)(h2 + (size_t)i * 384 + h * 128);
    const float4* as = (const float4*)(a_src2 + h * 128);
    const float4* ad = (const float4*)(a_dst2 + h * 128);
    float s = 0.f, t = 0.f;
#pragma unroll
    for (int d = 0; d < 32; ++d) {
        float4 hv = hp[d], av = as[d], bv = ad[d];
        s += hv.x * av.x + hv.y * av.y + hv.z * av.z + hv.w * av.w;
        t += hv.x * bv.x + hv.y * bv.y + hv.z * bv.z + hv.w * bv.w;
    }
    s2[idx] = s;
    t2[idx] = t;
}

// ---------- K8: mean-pool over jobs + mask passthrough ----------
__global__ void k8_pool(const float* __restrict__ f2, const float* __restrict__ mask,
                        float* __restrict__ out) {
    int idx = blockIdx.x * 256 + threadIdx.x;
    if (idx < 2048) {
        int b = idx >> 6, d = idx & 63;
        float s = 0.f;
        for (int j = 0; j < 150; ++j) s += f2[(size_t)(b * 150 + j) * 64 + d];
        out[idx] = s * (1.f / 150.f);
    } else if (idx < 2048 + 4832) {
        out[idx] = mask[idx - 2048];
    }
}

extern "C" void kernel_launch(void* const* d_in, const int* in_sizes, int n_in,
                              void* d_out, int out_size, void* d_ws, size_t ws_size,
                              hipStream_t stream) {
    const float* flat   = (const float*)d_in[0];
    const float* amask  = (const float*)d_in[1];
    const float* W1     = (const float*)d_in[2];
    const float* a_src1 = (const float*)d_in[3];
    const float* a_dst1 = (const float*)d_in[4];
    const float* W2     = (const float*)d_in[5];
    const float* a_src2 = (const float*)d_in[6];
    const float* a_dst2 = (const float*)d_in[7];
    const float* P1     = (const float*)d_in[8];
    const float* b1     = (const float*)d_in[9];
    const float* P2     = (const float*)d_in[10];
    const float* b2     = (const float*)d_in[11];
    float* out = (float*)d_out;

    float* ws = (float*)d_ws;
    // float-offset layout (30.2 MB total; all short/f32x4 bases 16B-aligned, doubles 8B-aligned)
    float*  h1      = ws + 0;                       // 921600 f  (dead after phC-L1)
    short*  gbf     = (short*)(ws + 0);             // 384000 f  (written at kout2, h1 dead)
    short*  f1bf    = (short*)(ws + 384000);        // 307200 f
    float*  s1      = ws + 921600;                  // 14400
    float*  t1      = ws + 936000;                  // 14400
    float*  s2      = ws + 950400;                  // 14400
    float*  t2      = ws + 964800;                  // 14400
    float*  e1      = ws + 979200;                  // 14400
    float*  e2      = ws + 993600;                  // 14400
    int*    inv     = (int*)(ws + 1008000);         // 14400
    int*    rk      = (int*)(ws + 1022400);         // 14400
    int*    partial = (int*)(ws + 1036800);         // 8*3*9600 = 230400
    double* Tot1    = (double*)(ws + 1267200);      // 3*64*129 dbl = 49536 f
    double* Tot2    = (double*)(ws + 1316736);      // 49536 f
    double* Off1    = (double*)(ws + 1366272);      // 49536 f
    double* Off2    = (double*)(ws + 1415808);      // 49536 f
    short*  h1abf   = (short*)(ws + 1465344);       // 460800 f
    float*  Suf1    = ws + 1926144;                 // 3*4801*129 = 1857987 -> pad 1857988
    float*  Pre2    = ws + 3784132;                 // 1857988
    float*  h2      = ws + 5642120;                 // 1843200 (dead after phC-L2)
    float*  f2      = ws + 5642120;                 // 307200 (aliases h2)
    short*  W2T     = (short*)(ws + 7485320);       // 36864 f
    short*  P1T     = (short*)(ws + 7522184);       // 10240 f
    short*  P2T     = (short*)(ws + 7532424);       // 4096 f -> total 7536520 f

    k0_prep<<<400, 256, 0, stream>>>(W2, P1, P2, W2T, P1T, P2T);
    k1_h1<<<NN, 192, 0, stream>>>(flat, W1, a_src1, a_dst1, h1, s1, t1);

    // ---- layer 1 attention (O(N*D) separable path) ----
    krank<<<dim3(38, 3, KCH), 256, 0, stream>>>(s1, t1, partial);
    krankred<<<113, 256, 0, stream>>>(t1, partial, inv, rk, e1, e2);
    phA<<<dim3(NCHUNK, 3), 128, 0, stream>>>(h1, inv, e1, e2, Tot1, Tot2, 192, 64, 65);
    phB<<<2, 256, 0, stream>>>(Tot1, Tot2, Off1, Off2, 65);
    phC<<<dim3(NCHUNK, 3), 128, 0, stream>>>(h1, inv, e1, e2, Off1, Off2, Suf1, Pre2, 192, 64, 65);
    kout1<<<NN, 192, 0, stream>>>(s1, rk, Suf1, Pre2, h1abf);

    gemm_bf16<<<dim3(75, 6), 256, 0, stream>>>(h1abf, W2T, nullptr, h2, nullptr, 384, 192, 0);
    k5_st2<<<57, 256, 0, stream>>>(h2, a_src2, a_dst2, s2, t2);

    // ---- layer 2 attention ----
    krank<<<dim3(38, 3, KCH), 256, 0, stream>>>(s2, t2, partial);
    krankred<<<113, 256, 0, stream>>>(t2, partial, inv, rk, e1, e2);
    phA<<<dim3(NCHUNK, 3), 192, 0, stream>>>(h2, inv, e1, e2, Tot1, Tot2, 384, 128, 129);
    phB<<<4, 256, 0, stream>>>(Tot1, Tot2, Off1, Off2, 129);
    phC<<<dim3(NCHUNK, 3), 192, 0, stream>>>(h2, inv, e1, e2, Off1, Off2, Suf1, Pre2, 384, 128, 129);
    kout2<<<NN, 192, 0, stream>>>(s2, rk, Suf1, Pre2, flat, gbf);

    gemm_bf16<<<dim3(75, 2), 256, 0, stream>>>(gbf, P1T, b1, nullptr, f1bf, 128, 160, 1);
    gemm_bf16<<<dim3(75, 1), 256, 0, stream>>>(f1bf, P2T, b2, f2, nullptr, 64, 128, 1);
    k8_pool<<<27, 256, 0, stream>>>(f2, amask, out);
}

// Round 3
// 283.223 us; speedup vs baseline: 1.1323x; 1.1111x over previous
//
#include <hip/hip_runtime.h>
#include <hip/hip_bf16.h>

typedef __attribute__((ext_vector_type(8))) short short8;
typedef __attribute__((ext_vector_type(4))) float f32x4;

__device__ __forceinline__ short bf16rne(float x) {
    unsigned u = __float_as_uint(x);
    u = (u + 0x7FFFu + ((u >> 16) & 1u)) >> 16;
    return (short)u;
}

#define NN 4800
#define NC 240       // scan chunks
#define CL 20        // 240*20 = 4800
#define KCH 8
#define KLEN 600     // 8*600 = 4800

// ---------- K0: weight transposes to bf16 ----------
__global__ void k0_prep(const float* __restrict__ W2, const float* __restrict__ P1,
                        const float* __restrict__ P2,
                        short* __restrict__ W2T, short* __restrict__ P1T, short* __restrict__ P2T) {
    int idx = blockIdx.x * 256 + threadIdx.x;
    if (idx < 73728) { int n = idx / 192, k = idx % 192; W2T[idx] = bf16rne(W2[k * 384 + n]); return; }
    idx -= 73728;
    if (idx < 20480) { int n = idx / 160, k = idx % 160; P1T[idx] = bf16rne(k < 143 ? P1[k * 128 + n] : 0.f); return; }
    idx -= 20480;
    if (idx < 8192)  { int n = idx / 128, k = idx % 128; P2T[idx] = bf16rne(P2[k * 64 + n]); }
}

// ---------- K1: h1 = flat @ W1 ; s1/t1 head dots ----------
__global__ void k1_h1(const float* __restrict__ flat, const float* __restrict__ W1,
                      const float* __restrict__ a_src, const float* __restrict__ a_dst,
                      float* __restrict__ h1, float* __restrict__ s1, float* __restrict__ t1) {
    __shared__ float fl[16];
    const int i = blockIdx.x, tid = threadIdx.x;
    if (tid < 15) fl[tid] = flat[i * 15 + tid];
    __syncthreads();
    float hv = 0.f;
#pragma unroll
    for (int f = 0; f < 15; ++f) hv += fl[f] * W1[f * 192 + tid];
    h1[(size_t)i * 192 + tid] = hv;
    float ps = hv * a_src[tid];
    float pt = hv * a_dst[tid];
#pragma unroll
    for (int off = 32; off; off >>= 1) {
        ps += __shfl_xor(ps, off);
        pt += __shfl_xor(pt, off);
    }
    if ((tid & 63) == 0) {
        int h = tid >> 6;
        s1[h * NN + i] = ps;
        t1[h * NN + i] = pt;
    }
}

// ---------- krank: partial rank counts. grid (38, 3, KCH) ----------
__global__ void krank(const float* __restrict__ s, const float* __restrict__ t,
                      int* __restrict__ partial) {
    __shared__ float ts[KLEN];
    const int h = blockIdx.y, kc = blockIdx.z;
    const float* tb_ = t + h * NN + kc * KLEN;
    for (int k = threadIdx.x; k < KLEN; k += 256) ts[k] = tb_[k];
    __syncthreads();
    int q = blockIdx.x * 256 + threadIdx.x;
    if (q >= 2 * NN) return;
    float u; int tb;
    if (q < NN) { u = t[h * NN + q]; tb = q - kc * KLEN; }   // local-index tiebreak
    else        { u = -s[h * NN + q - NN]; tb = KLEN; }       // <= semantics
    int cnt = 0;
#pragma unroll 8
    for (int k = 0; k < KLEN; ++k) {
        float tk = ts[k];
        cnt += (tk < u) || (tk == u && k < tb);
    }
    partial[(kc * 3 + h) * (2 * NN) + q] = cnt;
}

// ---------- krankred: sum partials -> inv perm, ranks, exp tables ----------
__global__ void krankred(const float* __restrict__ t, const int* __restrict__ partial,
                         int* __restrict__ inv, int* __restrict__ rk,
                         float* __restrict__ e1, float* __restrict__ e2) {
    int idx = blockIdx.x * 256 + threadIdx.x;
    if (idx >= 3 * 2 * NN) return;
    int h = idx / (2 * NN), q = idx % (2 * NN);
    int sum = 0;
#pragma unroll
    for (int kc = 0; kc < KCH; ++kc) sum += partial[(kc * 3 + h) * (2 * NN) + q];
    if (q < NN) {
        float tv = t[h * NN + q];
        e1[h * NN + q] = __expf(tv);
        e2[h * NN + q] = __expf(0.2f * tv);
        inv[h * NN + sum] = q;          // bijection via index tiebreak
    } else {
        rk[h * NN + q - NN] = sum;
    }
}

// ---------- phA: chunk totals. grid (NC, 3), block >= Dc ----------
__global__ void phA(const float* __restrict__ hsrc, const int* __restrict__ inv,
                    const float* __restrict__ e1, const float* __restrict__ e2,
                    float* __restrict__ Tot1, float* __restrict__ Tot2,
                    int HD, int Dd, int Dc) {
    const int c = blockIdx.x, h = blockIdx.y, d = threadIdx.x;
    if (d >= Dc) return;
    float hv[CL], w1[CL], w2[CL];
#pragma unroll
    for (int p0 = 0; p0 < CL; ++p0) {
        int j = inv[h * NN + c * CL + p0];
        hv[p0] = (d < Dd) ? hsrc[(size_t)j * HD + h * Dd + d] : 1.f;
        w1[p0] = e1[h * NN + j];
        w2[p0] = e2[h * NN + j];
    }
    float a1 = 0.f, a2 = 0.f;
#pragma unroll
    for (int p0 = 0; p0 < CL; ++p0) {
        a1 += w1[p0] * hv[p0];
        a2 += w2[p0] * hv[p0];
    }
    Tot1[(h * NC + c) * Dc + d] = a1;
    Tot2[(h * NC + c) * Dc + d] = a2;
}

// ---------- phB: scan chunk totals -> chunk offsets (fp64 accumulator) ----------
__global__ void phB(const float* __restrict__ Tot1, const float* __restrict__ Tot2,
                    float* __restrict__ Off1, float* __restrict__ Off2, int Dc) {
    int idx = blockIdx.x * 256 + threadIdx.x;
    if (idx >= 3 * Dc * 2) return;
    int dir = idx / (3 * Dc);
    int rest = idx % (3 * Dc);
    int h = rest / Dc, d = rest % Dc;
    if (dir == 0) {           // suffix offsets (exclusive from the top) for e1
        double r = 0;
        Off1[(h * NC + NC - 1) * Dc + d] = 0.f;
#pragma unroll 8
        for (int c = NC - 2; c >= 0; --c) {
            r += (double)Tot1[(h * NC + c + 1) * Dc + d];
            Off1[(h * NC + c) * Dc + d] = (float)r;
        }
    } else {                  // prefix offsets (exclusive) for e2
        double r = 0;
        Off2[(h * NC + 0) * Dc + d] = 0.f;
#pragma unroll 8
        for (int c = 1; c < NC; ++c) {
            r += (double)Tot2[(h * NC + c - 1) * Dc + d];
            Off2[(h * NC + c) * Dc + d] = (float)r;
        }
    }
}

// ---------- phC: write full prefix (exclusive, e2) / suffix (inclusive, e1) arrays ----------
__global__ void phC(const float* __restrict__ hsrc, const int* __restrict__ inv,
                    const float* __restrict__ e1, const float* __restrict__ e2,
                    const float* __restrict__ Off1, const float* __restrict__ Off2,
                    float* __restrict__ Suf1, float* __restrict__ Pre2,
                    int HD, int Dd, int Dc) {
    const int c = blockIdx.x, h = blockIdx.y, d = threadIdx.x;
    if (d >= Dc) return;
    float hv[CL], w1[CL], w2[CL];
#pragma unroll
    for (int p0 = 0; p0 < CL; ++p0) {
        int j = inv[h * NN + c * CL + p0];
        hv[p0] = (d < Dd) ? hsrc[(size_t)j * HD + h * Dd + d] : 1.f;
        w1[p0] = e1[h * NN + j];
        w2[p0] = e2[h * NN + j];
    }
    float r2 = Off2[(h * NC + c) * Dc + d];
#pragma unroll
    for (int p0 = 0; p0 < CL; ++p0) {
        int p = c * CL + p0;
        Pre2[((size_t)h * (NN + 1) + p) * Dc + d] = r2;
        r2 += w2[p0] * hv[p0];
    }
    if (c == NC - 1) {
        Pre2[((size_t)h * (NN + 1) + NN) * Dc + d] = r2;
        Suf1[((size_t)h * (NN + 1) + NN) * Dc + d] = 0.f;
    }
    float r1 = Off1[(h * NC + c) * Dc + d];
#pragma unroll
    for (int p0 = CL - 1; p0 >= 0; --p0) {
        int p = c * CL + p0;
        r1 += w1[p0] * hv[p0];
        Suf1[((size_t)h * (NN + 1) + p) * Dc + d] = r1;
    }
}

// ---------- kout1: combine + ELU -> h1a bf16 [4800][192]. grid 4800, block 192 ----------
__global__ void kout1(const float* __restrict__ s, const int* __restrict__ rk,
                      const float* __restrict__ Suf1, const float* __restrict__ Pre2,
                      short* __restrict__ h1abf) {
    const int i = blockIdx.x, tid = threadIdx.x;
    const int h = tid >> 6, d = tid & 63;
    float sv = s[h * NN + i];
    float es1 = __expf(sv), es2 = __expf(0.2f * sv);
    int r = rk[h * NN + i];
    size_t base = ((size_t)h * (NN + 1) + r) * 65;
    float num = es1 * Suf1[base + d] + es2 * Pre2[base + d];
    float den = es1 * Suf1[base + 64] + es2 * Pre2[base + 64];
    float v = num / den;
    v = v > 0.f ? v : (__expf(v) - 1.f);
    h1abf[(size_t)i * 192 + tid] = bf16rne(v);
}

// ---------- kout2: combine + head-mean + concat flat -> g bf16 [4800][160]. block 192 ----------
__global__ void kout2(const float* __restrict__ s, const int* __restrict__ rk,
                      const float* __restrict__ Suf1, const float* __restrict__ Pre2,
                      const float* __restrict__ flat, short* __restrict__ gbf) {
    const int i = blockIdx.x, tid = threadIdx.x;
    if (tid < 128) {
        float acc = 0.f;
#pragma unroll
        for (int h = 0; h < 3; ++h) {
            float sv = s[h * NN + i];
            float es1 = __expf(sv), es2 = __expf(0.2f * sv);
            int r = rk[h * NN + i];
            size_t base = ((size_t)h * (NN + 1) + r) * 129;
            float num = es1 * Suf1[base + tid] + es2 * Pre2[base + tid];
            float den = es1 * Suf1[base + 128] + es2 * Pre2[base + 128];
            acc += num / den;
        }
        gbf[(size_t)i * 160 + tid] = bf16rne(acc * (1.f / 3.f));
    } else if (tid < 160) {
        float v = (tid < 143) ? flat[i * 15 + (tid - 128)] : 0.f;
        gbf[(size_t)i * 160 + tid] = bf16rne(v);
    }
}

// ---------- generic bf16 MFMA GEMM: C[M,N] = A[M,K] @ BT[N,K]^T (+bias, relu) ----------
__global__ __launch_bounds__(256) void gemm_bf16(const short* __restrict__ A, const short* __restrict__ BT,
                                                 const float* __restrict__ bias,
                                                 float* __restrict__ Cf, short* __restrict__ Cb,
                                                 int N, int K, int relu) {
    const int tid = threadIdx.x;
    const int lane = tid & 63;
    const int w = tid >> 6;
    const int q = lane >> 4;
    const int mr = lane & 15;
    const int m = blockIdx.x * 64 + w * 16 + mr;
    const int n0 = blockIdx.y * 64;

    f32x4 acc[4];
#pragma unroll
    for (int n = 0; n < 4; ++n) acc[n] = (f32x4){0.f, 0.f, 0.f, 0.f};

    for (int k0 = 0; k0 < K; k0 += 32) {
        short8 af = *(const short8*)(A + (size_t)m * K + k0 + q * 8);
#pragma unroll
        for (int n = 0; n < 4; ++n) {
            short8 bf = *(const short8*)(BT + (size_t)(n0 + n * 16 + mr) * K + k0 + q * 8);
            acc[n] = __builtin_amdgcn_mfma_f32_16x16x32_bf16(af, bf, acc[n], 0, 0, 0);
        }
    }
#pragma unroll
    for (int n = 0; n < 4; ++n) {
        int col = n0 + n * 16 + mr;
        float bv = bias ? bias[col] : 0.f;
#pragma unroll
        for (int r = 0; r < 4; ++r) {
            int row = blockIdx.x * 64 + w * 16 + q * 4 + r;
            float v = acc[n][r] + bv;
            if (relu) v = fmaxf(v, 0.f);
            if (Cf) Cf[(size_t)row * N + col] = v;
            if (Cb) Cb[(size_t)row * N + col] = bf16rne(v);
        }
    }
}

// ---------- K5: s2/t2 head dots from h2 [4800][384] ----------
__global__ void k5_st2(const float* __restrict__ h2, const float* __restrict__ a_src2,
                       const float* __restrict__ a_dst2, float* __restrict__ s2, float* __restrict__ t2) {
    int idx = blockIdx.x * 256 + threadIdx.x;
    if (idx >= 3 * NN) return;
    int h = idx / NN, i = idx % NN;
    const float4* hp = (const float4*)(h2 + (size_t)i * 384 + h * 128);
    const float4* as = (const float4*)(a_src2 + h * 128);
    const float4* ad = (const float4*)(a_dst2 + h * 128);
    float s = 0.f, t = 0.f;
#pragma unroll
    for (int d = 0; d < 32; ++d) {
        float4 hv = hp[d], av = as[d], bv = ad[d];
        s += hv.x * av.x + hv.y * av.y + hv.z * av.z + hv.w * av.w;
        t += hv.x * bv.x + hv.y * bv.y + hv.z * bv.z + hv.w * bv.w;
    }
    s2[idx] = s;
    t2[idx] = t;
}

// ---------- K8: mean-pool over jobs + mask passthrough ----------
__global__ void k8_pool(const float* __restrict__ f2, const float* __restrict__ mask,
                        float* __restrict__ out) {
    int idx = blockIdx.x * 256 + threadIdx.x;
    if (idx < 2048) {
        int b = idx >> 6, d = idx & 63;
        float s = 0.f;
#pragma unroll 10
        for (int j = 0; j < 150; ++j) s += f2[(size_t)(b * 150 + j) * 64 + d];
        out[idx] = s * (1.f / 150.f);
    } else if (idx < 2048 + 4832) {
        out[idx] = mask[idx - 2048];
    }
}

extern "C" void kernel_launch(void* const* d_in, const int* in_sizes, int n_in,
                              void* d_out, int out_size, void* d_ws, size_t ws_size,
                              hipStream_t stream) {
    const float* flat   = (const float*)d_in[0];
    const float* amask  = (const float*)d_in[1];
    const float* W1     = (const float*)d_in[2];
    const float* a_src1 = (const float*)d_in[3];
    const float* a_dst1 = (const float*)d_in[4];
    const float* W2     = (const float*)d_in[5];
    const float* a_src2 = (const float*)d_in[6];
    const float* a_dst2 = (const float*)d_in[7];
    const float* P1     = (const float*)d_in[8];
    const float* b1     = (const float*)d_in[9];
    const float* P2     = (const float*)d_in[10];
    const float* b2     = (const float*)d_in[11];
    float* out = (float*)d_out;

    float* ws = (float*)d_ws;
    // float-offset layout (~30.8 MB total)
    float*  h1      = ws + 0;                       // 921600 f  (dead after phC-L1)
    short*  gbf     = (short*)(ws + 0);             // 384000 f  (written at kout2; h1 dead)
    short*  f1bf    = (short*)(ws + 384000);        // 307200 f
    float*  s1      = ws + 921600;                  // 14400
    float*  t1      = ws + 936000;                  // 14400
    float*  s2      = ws + 950400;                  // 14400
    float*  t2      = ws + 964800;                  // 14400
    float*  e1      = ws + 979200;                  // 14400
    float*  e2      = ws + 993600;                  // 14400
    int*    inv     = (int*)(ws + 1008000);         // 14400
    int*    rk      = (int*)(ws + 1022400);         // 14400
    int*    partial = (int*)(ws + 1036800);         // 230400
    float*  Tot1    = ws + 1267200;                 // 3*240*129 = 92880
    float*  Tot2    = ws + 1360080;                 // 92880
    float*  Off1    = ws + 1452960;                 // 92880
    float*  Off2    = ws + 1545840;                 // 92880
    short*  h1abf   = (short*)(ws + 1638720);       // 460800 f
    float*  Suf1    = ws + 2099520;                 // 3*4801*129 = 1857987 -> pad 1857988
    float*  Pre2    = ws + 3957508;                 // 1857988
    float*  h2      = ws + 5815496;                 // 1843200 (dead after phC-L2)
    float*  f2      = ws + 5815496;                 // 307200 (aliases h2)
    short*  W2T     = (short*)(ws + 7658696);       // 36864 f
    short*  P1T     = (short*)(ws + 7695560);       // 10240 f
    short*  P2T     = (short*)(ws + 7705800);       // 4096 f -> total 7709896 f

    k0_prep<<<400, 256, 0, stream>>>(W2, P1, P2, W2T, P1T, P2T);
    k1_h1<<<NN, 192, 0, stream>>>(flat, W1, a_src1, a_dst1, h1, s1, t1);

    // ---- layer 1 attention (O(N*D) separable path) ----
    krank<<<dim3(38, 3, KCH), 256, 0, stream>>>(s1, t1, partial);
    krankred<<<113, 256, 0, stream>>>(t1, partial, inv, rk, e1, e2);
    phA<<<dim3(NC, 3), 128, 0, stream>>>(h1, inv, e1, e2, Tot1, Tot2, 192, 64, 65);
    phB<<<2, 256, 0, stream>>>(Tot1, Tot2, Off1, Off2, 65);
    phC<<<dim3(NC, 3), 128, 0, stream>>>(h1, inv, e1, e2, Off1, Off2, Suf1, Pre2, 192, 64, 65);
    kout1<<<NN, 192, 0, stream>>>(s1, rk, Suf1, Pre2, h1abf);

    gemm_bf16<<<dim3(75, 6), 256, 0, stream>>>(h1abf, W2T, nullptr, h2, nullptr, 384, 192, 0);
    k5_st2<<<57, 256, 0, stream>>>(h2, a_src2, a_dst2, s2, t2);

    // ---- layer 2 attention ----
    krank<<<dim3(38, 3, KCH), 256, 0, stream>>>(s2, t2, partial);
    krankred<<<113, 256, 0, stream>>>(t2, partial, inv, rk, e1, e2);
    phA<<<dim3(NC, 3), 192, 0, stream>>>(h2, inv, e1, e2, Tot1, Tot2, 384, 128, 129);
    phB<<<4, 256, 0, stream>>>(Tot1, Tot2, Off1, Off2, 129);
    phC<<<dim3(NC, 3), 192, 0, stream>>>(h2, inv, e1, e2, Off1, Off2, Suf1, Pre2, 384, 128, 129);
    kout2<<<NN, 192, 0, stream>>>(s2, rk, Suf1, Pre2, flat, gbf);

    gemm_bf16<<<dim3(75, 2), 256, 0, stream>>>(gbf, P1T, b1, nullptr, f1bf, 128, 160, 1);
    gemm_bf16<<<dim3(75, 1), 256, 0, stream>>>(f1bf, P2T, b2, f2, nullptr, 64, 128, 1);
    k8_pool<<<27, 256, 0, stream>>>(f2, amask, out);
}